// Round 4
// baseline (2064.029 us; speedup 1.0000x reference)
//
#include <hip/hip_runtime.h>
#include <hip/hip_bf16.h>

#define B_ 4
#define N_ 16384
#define S_ 1024
#define K_ 32

typedef float f32x2 __attribute__((ext_vector_type(2)));

__device__ __forceinline__ f32x2 pk_add(f32x2 a, f32x2 b) {
  f32x2 d;
  asm("v_pk_add_f32 %0, %1, %2" : "=v"(d) : "v"(a), "v"(b));
  return d;
}
__device__ __forceinline__ f32x2 pk_mul(f32x2 a, f32x2 b) {
  f32x2 d;
  asm("v_pk_mul_f32 %0, %1, %2" : "=v"(d) : "v"(a), "v"(b));
  return d;
}

// wave64 max of nonnegative floats via DPP (identity 0 from bound_ctrl fill).
__device__ __forceinline__ float wave_max_nonneg(float x) {
#define DPPSTEP(ctrl, rm)                                                              \
  {                                                                                    \
    int s_ = __builtin_amdgcn_update_dpp(__float_as_int(x), __float_as_int(x), (ctrl), \
                                         (rm), 0xf, true);                             \
    x = fmaxf(x, __int_as_float(s_));                                                  \
  }
  DPPSTEP(0x111, 0xf)  // row_shr:1
  DPPSTEP(0x112, 0xf)  // row_shr:2
  DPPSTEP(0x114, 0xf)  // row_shr:4
  DPPSTEP(0x118, 0xf)  // row_shr:8
  DPPSTEP(0x142, 0xa)  // row_bcast:15 -> rows 1,3
  DPPSTEP(0x143, 0xc)  // row_bcast:31 -> rows 2,3
#undef DPPSTEP
  return __int_as_float(__builtin_amdgcn_readlane(__float_as_int(x), 63));
}

// wave64 max of u32 (identity 0).
__device__ __forceinline__ unsigned wave_umax(unsigned x) {
#define DPPSTEP(ctrl, rm)                                                             \
  {                                                                                   \
    unsigned s_ = (unsigned)__builtin_amdgcn_update_dpp((int)x, (int)x, (ctrl), (rm), \
                                                        0xf, true);                   \
    x = (x > s_) ? x : s_;                                                            \
  }
  DPPSTEP(0x111, 0xf)
  DPPSTEP(0x112, 0xf)
  DPPSTEP(0x114, 0xf)
  DPPSTEP(0x118, 0xf)
  DPPSTEP(0x142, 0xa)
  DPPSTEP(0x143, 0xc)
#undef DPPSTEP
  return (unsigned)__builtin_amdgcn_readlane((int)x, 63);
}

// ---------------- transpose features [B,64,N] -> [B,N,64] ----------------
__global__ __launch_bounds__(256) void k_transpose(const float* __restrict__ f,
                                                   float* __restrict__ ft) {
  __shared__ float tile[64][65];
  int b = blockIdx.x >> 8;
  int n0 = (blockIdx.x & 255) << 6;
  int t = threadIdx.x;
  int r = t >> 6, c = t & 63;
#pragma unroll
  for (int i = 0; i < 16; ++i) {
    int ch = r + i * 4;
    tile[ch][c] = f[((size_t)b * 64 + ch) * N_ + n0 + c];
  }
  __syncthreads();
#pragma unroll
  for (int i = 0; i < 16; ++i) {
    int n = r + i * 4;
    ft[((size_t)b * N_ + n0 + n) * 64 + c] = tile[c][n];
  }
}

// ---------------- furthest point sampling: 1 block per batch ----------------
// Coordinate storage: (x,y) pairs live in 128 KB static LDS as 16B entries
// {x_a, x_b, y_a, y_b} read with ds_read_b128 (16B/lane stride: conflict-free).
// z + running min-dist stay in registers (~32 floats -> no allocator pressure,
// no load sinking). Each thread only touches its own LDS entries (no barrier
// needed for them). This converts the per-iteration 192KB/CU L1/L2 re-fetch
// (~3000 cy) into 128KB/CU LDS reads (~1100 cy) overlapped with VALU.
__global__ __attribute__((amdgpu_flat_work_group_size(1024, 1024)))
__attribute__((amdgpu_waves_per_eu(4, 4))) void k_fps(const float* __restrict__ xyz,
                                                      float* __restrict__ out) {
#pragma clang fp contract(off)
  const int b = blockIdx.x, t = threadIdx.x;
  const int lane = t & 63, w = t >> 6;
  const float* X = xyz + (size_t)b * N_ * 3;

  __shared__ float4 sxy[8192];  // 128 KB: entry q*1024+t = {x(2q), x(2q+1), y(2q), y(2q+1)} for point slot*1024+t
  __shared__ float lwm[16];
  __shared__ unsigned lwp[16];

  f32x2 pz0, pz1, pz2, pz3, pz4, pz5, pz6, pz7;
  float md0 = 1e10f, md1 = 1e10f, md2 = 1e10f, md3 = 1e10f;
  float md4 = 1e10f, md5 = 1e10f, md6 = 1e10f, md7 = 1e10f;
  float md8 = 1e10f, md9 = 1e10f, md10 = 1e10f, md11 = 1e10f;
  float md12 = 1e10f, md13 = 1e10f, md14 = 1e10f, md15 = 1e10f;

#define FPS_LOAD(q)                                   \
  {                                                   \
    const float* qa = X + (((2 * q) << 10) + t) * 3;  \
    const float* qb = X + (((2 * q + 1) << 10) + t) * 3; \
    float xa = qa[0], ya = qa[1], za = qa[2];         \
    float xb = qb[0], yb = qb[1], zb = qb[2];         \
    sxy[(q << 10) + t] = make_float4(xa, xb, ya, yb); \
    pz##q.x = za; pz##q.y = zb;                       \
  }
  FPS_LOAD(0)
  FPS_LOAD(1)
  FPS_LOAD(2)
  FPS_LOAD(3)
  FPS_LOAD(4)
  FPS_LOAD(5)
  FPS_LOAD(6)
  FPS_LOAD(7)
#undef FPS_LOAD

  int sel = 0;
  for (int it = 0;; ++it) {
    int ssel = __builtin_amdgcn_readfirstlane(sel);
    const float* cp = X + 3 * ssel;
    float cx = cp[0], cy = cp[1], cz = cp[2];
    if (t == 0) {
      float* o = out + ((size_t)b * S_ + it) * 3;
      o[0] = cx; o[1] = cy; o[2] = cz;
    }
    if (it == S_ - 1) break;

    f32x2 ncx, ncy, ncz;
    ncx.x = -cx; ncx.y = -cx;
    ncy.x = -cy; ncy.y = -cy;
    ncz.x = -cz; ncz.y = -cz;

    // d = ((dx*dx + dy*dy) + dz*dz), two points per packed op; md = min(md, d)
#define FPS_UPD(q, ma, mb)                                                    \
  {                                                                           \
    float4 v = sxy[(q << 10) + t];                                            \
    f32x2 px, py;                                                             \
    px.x = v.x; px.y = v.y;                                                   \
    py.x = v.z; py.y = v.w;                                                   \
    f32x2 dx = pk_add(px, ncx);                                               \
    f32x2 dy = pk_add(py, ncy);                                               \
    f32x2 dz = pk_add(pz##q, ncz);                                            \
    f32x2 s = pk_add(pk_add(pk_mul(dx, dx), pk_mul(dy, dy)), pk_mul(dz, dz)); \
    ma = fminf(ma, s.x);                                                      \
    mb = fminf(mb, s.y);                                                      \
  }
    FPS_UPD(0, md0, md1)
    FPS_UPD(1, md2, md3)
    FPS_UPD(2, md4, md5)
    FPS_UPD(3, md6, md7)
    FPS_UPD(4, md8, md9)
    FPS_UPD(5, md10, md11)
    FPS_UPD(6, md12, md13)
    FPS_UPD(7, md14, md15)
#undef FPS_UPD

    // per-thread max (max3-friendly grouping)
    float m0 = fmaxf(fmaxf(md0, md1), md2);
    float m1 = fmaxf(fmaxf(md3, md4), md5);
    float m2 = fmaxf(fmaxf(md6, md7), md8);
    float m3 = fmaxf(fmaxf(md9, md10), md11);
    float m4 = fmaxf(fmaxf(md12, md13), md14);
    float mymax = fmaxf(fmaxf(fmaxf(m0, m1), fmaxf(m2, m3)), fmaxf(m4, md15));

    float wm = wave_max_nonneg(mymax);
    if (lane == 0) lwm[w] = wm;
    __syncthreads();

    // every wave redundantly reduces the 16 partials -> block max, no 2nd barrier
    float mv = wave_max_nonneg(lwm[lane & 15]);

    // index resolution: only threads holding the block max scan their slots.
    unsigned pc = 0xFFFFFFFFu;
    if (mymax == mv) {
      int slot = 15;
      if (md14 == mv) slot = 14;
      if (md13 == mv) slot = 13;
      if (md12 == mv) slot = 12;
      if (md11 == mv) slot = 11;
      if (md10 == mv) slot = 10;
      if (md9 == mv) slot = 9;
      if (md8 == mv) slot = 8;
      if (md7 == mv) slot = 7;
      if (md6 == mv) slot = 6;
      if (md5 == mv) slot = 5;
      if (md4 == mv) slot = 4;
      if (md3 == mv) slot = 3;
      if (md2 == mv) slot = 2;
      if (md1 == mv) slot = 1;
      if (md0 == mv) slot = 0;
      pc = (((unsigned)slot) << 10) | (unsigned)t;  // global point index
    }
    // min index == max of (UMAX - p)
    unsigned r = wave_umax(0xFFFFFFFFu - pc);
    if (lane == 0) lwp[w] = r;
    __syncthreads();
    unsigned r2 = wave_umax(lwp[lane & 15]);
    sel = (int)(0xFFFFFFFFu - r2);
  }
}

// ---------------- ball query: 1 wave per center ----------------
__global__ __launch_bounds__(256) void k_ball(const float* __restrict__ xyz,
                                              const float* __restrict__ nx,
                                              int* __restrict__ bidx) {
#pragma clang fp contract(off)
  int gw = (blockIdx.x * 256 + threadIdx.x) >> 6;
  int l = threadIdx.x & 63;
  int b = gw >> 10;
  const float* X = xyz + (size_t)b * N_ * 3;
  float cx = nx[(size_t)gw * 3 + 0], cy = nx[(size_t)gw * 3 + 1], cz = nx[(size_t)gw * 3 + 2];
  float xn2 = (cx * cx + cy * cy) + cz * cz;
  int* out = bidx + gw * K_;
  int have = 0, first = -1;
  for (int n0 = 0; n0 < N_; n0 += 64) {
    int p = n0 + l;
    float x = X[p * 3 + 0], y = X[p * 3 + 1], z = X[p * 3 + 2];
    float pn2 = (x * x + y * y) + z * z;
    float dt = (x * cx + y * cy) + z * cz;
    float d2 = (xn2 + pn2) - 2.0f * dt;  // exact replica of ref's expanded form
    unsigned long long m = __ballot(d2 < 0.039999999105930328f);  // float(0.04), NOT 0.2f*0.2f
    if (first < 0 && m) first = n0 + (__ffsll(m) - 1);
    if (m & (1ull << l)) {
      int pos = have + __popcll(m & ((1ull << l) - 1ull));
      if (pos < K_) out[pos] = p;
    }
    have += __popcll(m);
    if (have >= K_) break;
  }
  if (have < K_ && l >= have && l < K_) out[l] = first;  // pad with first neighbor
}

// ---------------- gather + conv1 (67 -> 64), 8 centers per block ----------------
__global__ __launch_bounds__(256) void k_conv1(const float* __restrict__ xyz,
                                               const float* __restrict__ ft,
                                               const float* __restrict__ nx,
                                               const int* __restrict__ bidx,
                                               const float* __restrict__ W0,
                                               float* __restrict__ y1) {
  __shared__ float w0t[67][64];
  __shared__ float Xs[32][69];  // stride 69: (69k+i)%32 = (5k+i)%32 conflict-free
  __shared__ int lidx[32];
  __shared__ float lctr[3];
  const int t = threadIdx.x;
  for (int idx = t; idx < 67 * 64; idx += 256) {
    int i = idx >> 6, c = idx & 63;
    w0t[i][c] = W0[c * 67 + i];
  }
  const int k = t & 31, cb = (t >> 5) << 3;
  const int gk = t >> 3, c8 = (t & 7) << 3;
  for (int cc = 0; cc < 8; ++cc) {
    int cs = blockIdx.x * 8 + cc;
    int b = cs >> 10;
    __syncthreads();
    if (t < 32) lidx[t] = bidx[cs * K_ + t];
    if (t < 3) lctr[t] = nx[(size_t)cs * 3 + t];
    __syncthreads();
    {
      int p = lidx[gk];
      const float* src = ft + ((size_t)b * N_ + p) * 64 + c8;
      float4 v0 = *(const float4*)src;
      float4 v1 = *(const float4*)(src + 4);
      float* xr = &Xs[gk][3 + c8];
      xr[0] = v0.x; xr[1] = v0.y; xr[2] = v0.z; xr[3] = v0.w;
      xr[4] = v1.x; xr[5] = v1.y; xr[6] = v1.z; xr[7] = v1.w;
    }
    if (t < 32) {
      int p = lidx[t];
      const float* pp = xyz + ((size_t)b * N_ + p) * 3;
      Xs[t][0] = pp[0] - lctr[0];
      Xs[t][1] = pp[1] - lctr[1];
      Xs[t][2] = pp[2] - lctr[2];
    }
    __syncthreads();
    float acc[8] = {};
    for (int i = 0; i < 67; ++i) {
      float xv = Xs[k][i];
      const float4 wa = *(const float4*)&w0t[i][cb];
      const float4 wb = *(const float4*)&w0t[i][cb + 4];
      acc[0] = fmaf(wa.x, xv, acc[0]);
      acc[1] = fmaf(wa.y, xv, acc[1]);
      acc[2] = fmaf(wa.z, xv, acc[2]);
      acc[3] = fmaf(wa.w, xv, acc[3]);
      acc[4] = fmaf(wb.x, xv, acc[4]);
      acc[5] = fmaf(wb.y, xv, acc[5]);
      acc[6] = fmaf(wb.z, xv, acc[6]);
      acc[7] = fmaf(wb.w, xv, acc[7]);
    }
    float* dst = y1 + ((size_t)cs * K_ + k) * 64 + cb;
    *(float4*)dst = make_float4(acc[0], acc[1], acc[2], acc[3]);
    *(float4*)(dst + 4) = make_float4(acc[4], acc[5], acc[6], acc[7]);
  }
}

// ---------------- BN1 stats: per-block partials (deterministic) ----------------
__global__ __launch_bounds__(256) void k_stats1(const float* __restrict__ y1,
                                                float* __restrict__ part) {
  int t = threadIdx.x;
  int c = t & 63;
  float s = 0.f, q = 0.f;
  for (int row = blockIdx.x * 4 + (t >> 6); row < B_ * S_ * K_; row += 512 * 4) {
    float v = y1[(size_t)row * 64 + c];
    s += v;
    q = fmaf(v, v, q);
  }
  __shared__ float ls[4][64], lq[4][64];
  ls[t >> 6][c] = s;
  lq[t >> 6][c] = q;
  __syncthreads();
  if (t < 64) {
    float S = (ls[0][t] + ls[1][t]) + (ls[2][t] + ls[3][t]);
    float Q = (lq[0][t] + lq[1][t]) + (lq[2][t] + lq[3][t]);
    part[blockIdx.x * 128 + t] = S;
    part[blockIdx.x * 128 + 64 + t] = Q;
  }
}

// ---------------- reduce [nrow][ncol] partials -> [ncol] ----------------
__global__ void k_red(const float* __restrict__ part, float* __restrict__ outv,
                      int ncol, int nrow) {
  int c = blockIdx.x * 64 + threadIdx.x;
  float a0 = 0, a1 = 0, a2 = 0, a3 = 0;
  for (int r = 0; r < nrow; r += 4) {
    a0 += part[(size_t)(r + 0) * ncol + c];
    a1 += part[(size_t)(r + 1) * ncol + c];
    a2 += part[(size_t)(r + 2) * ncol + c];
    a3 += part[(size_t)(r + 3) * ncol + c];
  }
  outv[c] = (a0 + a1) + (a2 + a3);
}

// ------- BN1-apply + conv2 (64->128) + stats2 partials + max/min over K -------
__global__ __launch_bounds__(256) void k_conv2(const float* __restrict__ y1,
                                               const float* __restrict__ W1,
                                               const float* __restrict__ st1,
                                               const float* __restrict__ g0,
                                               const float* __restrict__ b0,
                                               float* __restrict__ part2,
                                               float* __restrict__ mmax,
                                               float* __restrict__ mmin) {
  __shared__ float w1t[64][128];
  __shared__ float X2[32][69];
  __shared__ float a1s[64], bb1s[64];
  const int t = threadIdx.x;
  if (t < 64) {
    float s = st1[t], q = st1[64 + t];
    float m = s * (1.f / 131072.f);
    float v = fmaxf(q * (1.f / 131072.f) - m * m, 0.f);
    float inv = 1.f / sqrtf(v + 1e-5f);
    float a = g0[t] * inv;
    a1s[t] = a;
    bb1s[t] = b0[t] - m * a;
  }
  for (int idx = t; idx < 64 * 128; idx += 256) {
    int i = idx >> 7, c = idx & 127;
    w1t[i][c] = W1[c * 64 + i];
  }
  const int kg = (t & 7) << 2;   // 4 neighbor slots
  const int cb = (t >> 3) << 2;  // 4 channels
  const int gk = t >> 3, c8 = (t & 7) << 3;
  float ts[4] = {}, tq[4] = {};
  for (int cc = 0; cc < 8; ++cc) {
    int cs = blockIdx.x * 8 + cc;
    int b = cs >> 10, sc = cs & 1023;
    __syncthreads();
    {
      const float* src = y1 + ((size_t)cs * K_ + gk) * 64 + c8;
      float4 v0 = *(const float4*)src;
      float4 v1 = *(const float4*)(src + 4);
      float vv[8] = {v0.x, v0.y, v0.z, v0.w, v1.x, v1.y, v1.z, v1.w};
#pragma unroll
      for (int j = 0; j < 8; ++j) {
        int c = c8 + j;
        X2[gk][c] = fmaxf(fmaf(a1s[c], vv[j], bb1s[c]), 0.f);
      }
    }
    __syncthreads();
    float acc[4][4] = {};
    for (int i = 0; i < 64; ++i) {
      const float4 w = *(const float4*)&w1t[i][cb];
#pragma unroll
      for (int kk = 0; kk < 4; ++kk) {
        float xv = X2[kg + kk][i];
        acc[kk][0] = fmaf(w.x, xv, acc[kk][0]);
        acc[kk][1] = fmaf(w.y, xv, acc[kk][1]);
        acc[kk][2] = fmaf(w.z, xv, acc[kk][2]);
        acc[kk][3] = fmaf(w.w, xv, acc[kk][3]);
      }
    }
    float mx[4], mn[4];
#pragma unroll
    for (int j = 0; j < 4; ++j) {
      mx[j] = fmaxf(fmaxf(acc[0][j], acc[1][j]), fmaxf(acc[2][j], acc[3][j]));
      mn[j] = fminf(fminf(acc[0][j], acc[1][j]), fminf(acc[2][j], acc[3][j]));
      ts[j] += (acc[0][j] + acc[1][j]) + (acc[2][j] + acc[3][j]);
      tq[j] += (acc[0][j] * acc[0][j] + acc[1][j] * acc[1][j]) +
               (acc[2][j] * acc[2][j] + acc[3][j] * acc[3][j]);
    }
#pragma unroll
    for (int off = 1; off < 8; off <<= 1) {
#pragma unroll
      for (int j = 0; j < 4; ++j) {
        mx[j] = fmaxf(mx[j], __shfl_xor(mx[j], off));
        mn[j] = fminf(mn[j], __shfl_xor(mn[j], off));
      }
    }
    if ((t & 7) == 0) {
#pragma unroll
      for (int j = 0; j < 4; ++j) {
        size_t o = ((size_t)b * 128 + cb + j) * 1024 + sc;
        mmax[o] = mx[j];
        mmin[o] = mn[j];
      }
    }
  }
#pragma unroll
  for (int off = 1; off < 8; off <<= 1) {
#pragma unroll
    for (int j = 0; j < 4; ++j) {
      ts[j] += __shfl_xor(ts[j], off);
      tq[j] += __shfl_xor(tq[j], off);
    }
  }
  if ((t & 7) == 0) {
#pragma unroll
    for (int j = 0; j < 4; ++j) {
      part2[blockIdx.x * 256 + cb + j] = ts[j];
      part2[blockIdx.x * 256 + 128 + cb + j] = tq[j];
    }
  }
}

// ---------------- finalize: BN2 affine on max/min + ReLU ----------------
__global__ __launch_bounds__(256) void k_final(const float* __restrict__ st2,
                                               const float* __restrict__ g1,
                                               const float* __restrict__ b1,
                                               const float* __restrict__ mmax,
                                               const float* __restrict__ mmin,
                                               float* __restrict__ out) {
  int tid = blockIdx.x * 256 + threadIdx.x;
  int c = (tid >> 10) & 127;
  float s = st2[c], q = st2[128 + c];
  float m = s * (1.f / 131072.f);
  float v = fmaxf(q * (1.f / 131072.f) - m * m, 0.f);
  float inv = 1.f / sqrtf(v + 1e-5f);
  float a = g1[c] * inv;
  float bb = b1[c] - m * a;
  // max over K of relu(a*x+bb) == relu(a * (a>=0 ? max : min) + bb)
  float x = (a >= 0.f) ? mmax[tid] : mmin[tid];
  out[12288 + tid] = fmaxf(fmaf(a, x, bb), 0.f);
}

extern "C" void kernel_launch(void* const* d_in, const int* in_sizes, int n_in,
                              void* d_out, int out_size, void* d_ws, size_t ws_size,
                              hipStream_t stream) {
  const float* xyz = (const float*)d_in[0];
  const float* features = (const float*)d_in[1];
  const float* W0 = (const float*)d_in[2];
  const float* g0 = (const float*)d_in[3];
  const float* b0 = (const float*)d_in[4];
  const float* W1 = (const float*)d_in[5];
  const float* g1 = (const float*)d_in[6];
  const float* b1 = (const float*)d_in[7];
  float* out = (float*)d_out;
  float* ws = (float*)d_ws;

  float* ft = ws;                                   // 4,194,304 f
  float* y1 = ft + (size_t)4 * 16384 * 64;          // 8,388,608 f
  float* part1 = y1 + (size_t)4 * 1024 * 32 * 64;   // 65,536 f
  float* part2 = part1 + 512 * 128;                 // 131,072 f
  float* st1 = part2 + 512 * 256;                   // 128 f
  float* st2 = st1 + 128;                           // 256 f
  float* mmax = st2 + 256;                          // 524,288 f
  float* mmin = mmax + (size_t)4 * 128 * 1024;      // 524,288 f
  int* bidx = (int*)(mmin + (size_t)4 * 128 * 1024);// 131,072 i
  if (ws_size < (size_t)(13828480 + 131072) * 4) return;  // workspace guard

  float* nxyz = out;  // new_xyz occupies out[0..12288)

  k_transpose<<<1024, 256, 0, stream>>>(features, ft);
  k_fps<<<4, 1024, 0, stream>>>(xyz, nxyz);
  k_ball<<<1024, 256, 0, stream>>>(xyz, nxyz, bidx);
  k_conv1<<<512, 256, 0, stream>>>(xyz, ft, nxyz, bidx, W0, y1);
  k_stats1<<<512, 256, 0, stream>>>(y1, part1);
  k_red<<<2, 64, 0, stream>>>(part1, st1, 128, 512);
  k_conv2<<<512, 256, 0, stream>>>(y1, W1, st1, g0, b0, part2, mmax, mmin);
  k_red<<<4, 64, 0, stream>>>(part2, st2, 256, 512);
  k_final<<<2048, 256, 0, stream>>>(st2, g1, b1, mmax, mmin, out);
}

// Round 5
// 1973.118 us; speedup vs baseline: 1.0461x; 1.0461x over previous
//
#include <hip/hip_runtime.h>
#include <hip/hip_bf16.h>

#define B_ 4
#define N_ 16384
#define S_ 1024
#define K_ 32

typedef float f32x2 __attribute__((ext_vector_type(2)));

__device__ __forceinline__ f32x2 pk_add(f32x2 a, f32x2 b) {
  f32x2 d;
  asm("v_pk_add_f32 %0, %1, %2" : "=v"(d) : "v"(a), "v"(b));
  return d;
}
__device__ __forceinline__ f32x2 pk_mul(f32x2 a, f32x2 b) {
  f32x2 d;
  asm("v_pk_mul_f32 %0, %1, %2" : "=v"(d) : "v"(a), "v"(b));
  return d;
}

// wave64 max of nonnegative floats via DPP (identity 0 from bound_ctrl fill).
__device__ __forceinline__ float wave_max_nonneg(float x) {
#define DPPSTEP(ctrl, rm)                                                              \
  {                                                                                    \
    int s_ = __builtin_amdgcn_update_dpp(__float_as_int(x), __float_as_int(x), (ctrl), \
                                         (rm), 0xf, true);                             \
    x = fmaxf(x, __int_as_float(s_));                                                  \
  }
  DPPSTEP(0x111, 0xf)  // row_shr:1
  DPPSTEP(0x112, 0xf)  // row_shr:2
  DPPSTEP(0x114, 0xf)  // row_shr:4
  DPPSTEP(0x118, 0xf)  // row_shr:8
  DPPSTEP(0x142, 0xa)  // row_bcast:15 -> rows 1,3
  DPPSTEP(0x143, 0xc)  // row_bcast:31 -> rows 2,3
#undef DPPSTEP
  return __int_as_float(__builtin_amdgcn_readlane(__float_as_int(x), 63));
}

// wave64 max of u32 (identity 0).
__device__ __forceinline__ unsigned wave_umax(unsigned x) {
#define DPPSTEP(ctrl, rm)                                                             \
  {                                                                                   \
    unsigned s_ = (unsigned)__builtin_amdgcn_update_dpp((int)x, (int)x, (ctrl), (rm), \
                                                        0xf, true);                   \
    x = (x > s_) ? x : s_;                                                            \
  }
  DPPSTEP(0x111, 0xf)
  DPPSTEP(0x112, 0xf)
  DPPSTEP(0x114, 0xf)
  DPPSTEP(0x118, 0xf)
  DPPSTEP(0x142, 0xa)
  DPPSTEP(0x143, 0xc)
#undef DPPSTEP
  return (unsigned)__builtin_amdgcn_readlane((int)x, 63);
}

// ---------------- transpose features [B,64,N] -> [B,N,64] ----------------
__global__ __launch_bounds__(256) void k_transpose(const float* __restrict__ f,
                                                   float* __restrict__ ft) {
  __shared__ float tile[64][65];
  int b = blockIdx.x >> 8;
  int n0 = (blockIdx.x & 255) << 6;
  int t = threadIdx.x;
  int r = t >> 6, c = t & 63;
#pragma unroll
  for (int i = 0; i < 16; ++i) {
    int ch = r + i * 4;
    tile[ch][c] = f[((size_t)b * 64 + ch) * N_ + n0 + c];
  }
  __syncthreads();
#pragma unroll
  for (int i = 0; i < 16; ++i) {
    int n = r + i * 4;
    ft[((size_t)b * N_ + n0 + n) * 64 + c] = tile[c][n];
  }
}

// ---------------- furthest point sampling: 1 block per batch ----------------
// xy pairs in LDS (128 KB, read back as native f32x2 -> no repack movs);
// z + running min-dist in registers. Block argmax via LDS atomics on
// ping-pong slots: per-wave atomicMax(float-bits) for the value, then only
// matcher waves scan + atomicMin(pc) where pc = slot<<10|t == global index
// (exact first-max tie-break). Winner publishes the NEGATED next-center
// coords to f32x2 LDS slots -> no global fetch on the critical path.
__global__ __attribute__((amdgpu_flat_work_group_size(1024, 1024)))
__attribute__((amdgpu_waves_per_eu(4, 4))) void k_fps(const float* __restrict__ xyz,
                                                      float* __restrict__ out) {
#pragma clang fp contract(off)
  const int b = blockIdx.x, t = threadIdx.x;
  const int lane = t & 63, w = t >> 6;
  const float* X = xyz + (size_t)b * N_ * 3;

  __shared__ float4 sxy[8192];  // entry (q<<10)+t = {x(2q), x(2q+1), y(2q), y(2q+1)} of pts slot*1024+t
  __shared__ f32x2 csx[16], csy[16], csz[16];  // winner-broadcast (negated) center coords
  __shared__ unsigned vslot[2], widx[2];       // ping-pong value/index slots

  f32x2 pz0, pz1, pz2, pz3, pz4, pz5, pz6, pz7;
  f32x2 md0, md1, md2, md3, md4, md5, md6, md7;
  md0 = md1 = md2 = md3 = md4 = md5 = md6 = md7 = (f32x2){1e10f, 1e10f};

#define FPS_LOAD(q)                                     \
  {                                                     \
    const float* qa = X + (((2 * q) << 10) + t) * 3;    \
    const float* qb = X + (((2 * q + 1) << 10) + t) * 3;\
    float xa = qa[0], ya = qa[1], za = qa[2];           \
    float xb = qb[0], yb = qb[1], zb = qb[2];           \
    sxy[(q << 10) + t] = make_float4(xa, xb, ya, yb);   \
    pz##q.x = za; pz##q.y = zb;                         \
  }
  FPS_LOAD(0)
  FPS_LOAD(1)
  FPS_LOAD(2)
  FPS_LOAD(3)
  FPS_LOAD(4)
  FPS_LOAD(5)
  FPS_LOAD(6)
  FPS_LOAD(7)
#undef FPS_LOAD

  // initial center = point 0 (one-time global broadcast read)
  float c0x = X[0], c0y = X[1], c0z = X[2];
  f32x2 ncx, ncy, ncz;  // negated center pair
  ncx.x = -c0x; ncx.y = -c0x;
  ncy.x = -c0y; ncy.y = -c0y;
  ncz.x = -c0z; ncz.y = -c0z;
  if (t == 0) { vslot[0] = 0u; widx[0] = 0xFFFFFFFFu; }
  __syncthreads();

  int sld = 0;
  for (int it = 0;; ++it) {
    if (t == 0) {
      float* o = out + ((size_t)b * S_ + it) * 3;
      o[0] = -ncx.x; o[1] = -ncy.x; o[2] = -ncz.x;
    }
    if (it == S_ - 1) break;

    // d = ((dx*dx + dy*dy) + dz*dz), two points per packed op; md = min(md, d)
#define FPS_UPD(q)                                                             \
  {                                                                            \
    const f32x2* pp = (const f32x2*)&sxy[((q) << 10) + t];                     \
    f32x2 px = pp[0], py = pp[1];                                              \
    f32x2 dx = pk_add(px, ncx);                                                \
    f32x2 dy = pk_add(py, ncy);                                                \
    f32x2 dz = pk_add(pz##q, ncz);                                             \
    f32x2 ss = pk_add(pk_add(pk_mul(dx, dx), pk_mul(dy, dy)), pk_mul(dz, dz)); \
    md##q.x = fminf(md##q.x, ss.x);                                            \
    md##q.y = fminf(md##q.y, ss.y);                                            \
  }
    FPS_UPD(0)
    FPS_UPD(1)
    FPS_UPD(2)
    FPS_UPD(3)
    FPS_UPD(4)
    FPS_UPD(5)
    FPS_UPD(6)
    FPS_UPD(7)
#undef FPS_UPD

    float a0 = fmaxf(fmaxf(md0.x, md0.y), fmaxf(md1.x, md1.y));
    float a1 = fmaxf(fmaxf(md2.x, md2.y), fmaxf(md3.x, md3.y));
    float a2 = fmaxf(fmaxf(md4.x, md4.y), fmaxf(md5.x, md5.y));
    float a3 = fmaxf(fmaxf(md6.x, md6.y), fmaxf(md7.x, md7.y));
    float mymax = fmaxf(fmaxf(a0, a1), fmaxf(a2, a3));

    float wm = wave_max_nonneg(mymax);
    if (lane == 63) atomicMax(&vslot[sld], __float_as_uint(wm));
    __syncthreads();  // barrier 1: block max ready

    float mvf = __uint_as_float(vslot[sld]);
    if (__ballot(mymax == mvf)) {  // wave-uniform: only matcher waves pay
      int slot = 15;
      if (md7.x == mvf) slot = 14;
      if (md6.y == mvf) slot = 13;
      if (md6.x == mvf) slot = 12;
      if (md5.y == mvf) slot = 11;
      if (md5.x == mvf) slot = 10;
      if (md4.y == mvf) slot = 9;
      if (md4.x == mvf) slot = 8;
      if (md3.y == mvf) slot = 7;
      if (md3.x == mvf) slot = 6;
      if (md2.y == mvf) slot = 5;
      if (md2.x == mvf) slot = 4;
      if (md1.y == mvf) slot = 3;
      if (md1.x == mvf) slot = 2;
      if (md0.y == mvf) slot = 1;
      if (md0.x == mvf) slot = 0;
      unsigned pc = (mymax == mvf) ? (((unsigned)slot << 10) | (unsigned)t) : 0xFFFFFFFFu;
      unsigned r = wave_umax(~pc);  // wave winner = min pc
      if ((~pc) == r) {             // unique winner lane of this wave
        int q = slot >> 1, hi = slot & 1;
        float4 v4 = sxy[(q << 10) + t];
        float xc = hi ? v4.y : v4.x;
        float yc = hi ? v4.w : v4.z;
        f32x2 zq = pz0;
        if (q == 1) zq = pz1;
        if (q == 2) zq = pz2;
        if (q == 3) zq = pz3;
        if (q == 4) zq = pz4;
        if (q == 5) zq = pz5;
        if (q == 6) zq = pz6;
        if (q == 7) zq = pz7;
        float zc = hi ? zq.y : zq.x;
        f32x2 tx, ty, tz;
        tx.x = -xc; tx.y = -xc;
        ty.x = -yc; ty.y = -yc;
        tz.x = -zc; tz.y = -zc;
        csx[w] = tx; csy[w] = ty; csz[w] = tz;
        atomicMin(&widx[sld], pc);
      }
    }
    // reset NEXT iteration's slots between the barriers (race-free)
    if (t == 0) { vslot[sld ^ 1] = 0u; widx[sld ^ 1] = 0xFFFFFFFFu; }
    __syncthreads();  // barrier 2: winner published

    unsigned wi = widx[sld];
    int wv = (int)(wi & 1023u) >> 6;
    ncx = csx[wv]; ncy = csy[wv]; ncz = csz[wv];
    sld ^= 1;
  }
}

// ---------------- ball query: 1 wave per center ----------------
__global__ __launch_bounds__(256) void k_ball(const float* __restrict__ xyz,
                                              const float* __restrict__ nx,
                                              int* __restrict__ bidx) {
#pragma clang fp contract(off)
  int gw = (blockIdx.x * 256 + threadIdx.x) >> 6;
  int l = threadIdx.x & 63;
  int b = gw >> 10;
  const float* X = xyz + (size_t)b * N_ * 3;
  float cx = nx[(size_t)gw * 3 + 0], cy = nx[(size_t)gw * 3 + 1], cz = nx[(size_t)gw * 3 + 2];
  float xn2 = (cx * cx + cy * cy) + cz * cz;
  int* out = bidx + gw * K_;
  int have = 0, first = -1;
  for (int n0 = 0; n0 < N_; n0 += 64) {
    int p = n0 + l;
    float x = X[p * 3 + 0], y = X[p * 3 + 1], z = X[p * 3 + 2];
    float pn2 = (x * x + y * y) + z * z;
    float dt = (x * cx + y * cy) + z * cz;
    float d2 = (xn2 + pn2) - 2.0f * dt;  // exact replica of ref's expanded form
    unsigned long long m = __ballot(d2 < 0.039999999105930328f);  // float(0.04), NOT 0.2f*0.2f
    if (first < 0 && m) first = n0 + (__ffsll(m) - 1);
    if (m & (1ull << l)) {
      int pos = have + __popcll(m & ((1ull << l) - 1ull));
      if (pos < K_) out[pos] = p;
    }
    have += __popcll(m);
    if (have >= K_) break;
  }
  if (have < K_ && l >= have && l < K_) out[l] = first;  // pad with first neighbor
}

// ---------------- gather + conv1 (67 -> 64), 8 centers per block ----------------
__global__ __launch_bounds__(256) void k_conv1(const float* __restrict__ xyz,
                                               const float* __restrict__ ft,
                                               const float* __restrict__ nx,
                                               const int* __restrict__ bidx,
                                               const float* __restrict__ W0,
                                               float* __restrict__ y1) {
  __shared__ float w0t[67][64];
  __shared__ float Xs[32][69];  // stride 69: (69k+i)%32 = (5k+i)%32 conflict-free
  __shared__ int lidx[32];
  __shared__ float lctr[3];
  const int t = threadIdx.x;
  for (int idx = t; idx < 67 * 64; idx += 256) {
    int i = idx >> 6, c = idx & 63;
    w0t[i][c] = W0[c * 67 + i];
  }
  const int k = t & 31, cb = (t >> 5) << 3;
  const int gk = t >> 3, c8 = (t & 7) << 3;
  for (int cc = 0; cc < 8; ++cc) {
    int cs = blockIdx.x * 8 + cc;
    int b = cs >> 10;
    __syncthreads();
    if (t < 32) lidx[t] = bidx[cs * K_ + t];
    if (t < 3) lctr[t] = nx[(size_t)cs * 3 + t];
    __syncthreads();
    {
      int p = lidx[gk];
      const float* src = ft + ((size_t)b * N_ + p) * 64 + c8;
      float4 v0 = *(const float4*)src;
      float4 v1 = *(const float4*)(src + 4);
      float* xr = &Xs[gk][3 + c8];
      xr[0] = v0.x; xr[1] = v0.y; xr[2] = v0.z; xr[3] = v0.w;
      xr[4] = v1.x; xr[5] = v1.y; xr[6] = v1.z; xr[7] = v1.w;
    }
    if (t < 32) {
      int p = lidx[t];
      const float* pp = xyz + ((size_t)b * N_ + p) * 3;
      Xs[t][0] = pp[0] - lctr[0];
      Xs[t][1] = pp[1] - lctr[1];
      Xs[t][2] = pp[2] - lctr[2];
    }
    __syncthreads();
    float acc[8] = {};
    for (int i = 0; i < 67; ++i) {
      float xv = Xs[k][i];
      const float4 wa = *(const float4*)&w0t[i][cb];
      const float4 wb = *(const float4*)&w0t[i][cb + 4];
      acc[0] = fmaf(wa.x, xv, acc[0]);
      acc[1] = fmaf(wa.y, xv, acc[1]);
      acc[2] = fmaf(wa.z, xv, acc[2]);
      acc[3] = fmaf(wa.w, xv, acc[3]);
      acc[4] = fmaf(wb.x, xv, acc[4]);
      acc[5] = fmaf(wb.y, xv, acc[5]);
      acc[6] = fmaf(wb.z, xv, acc[6]);
      acc[7] = fmaf(wb.w, xv, acc[7]);
    }
    float* dst = y1 + ((size_t)cs * K_ + k) * 64 + cb;
    *(float4*)dst = make_float4(acc[0], acc[1], acc[2], acc[3]);
    *(float4*)(dst + 4) = make_float4(acc[4], acc[5], acc[6], acc[7]);
  }
}

// ---------------- BN1 stats: per-block partials (deterministic) ----------------
__global__ __launch_bounds__(256) void k_stats1(const float* __restrict__ y1,
                                                float* __restrict__ part) {
  int t = threadIdx.x;
  int c = t & 63;
  float s = 0.f, q = 0.f;
  for (int row = blockIdx.x * 4 + (t >> 6); row < B_ * S_ * K_; row += 512 * 4) {
    float v = y1[(size_t)row * 64 + c];
    s += v;
    q = fmaf(v, v, q);
  }
  __shared__ float ls[4][64], lq[4][64];
  ls[t >> 6][c] = s;
  lq[t >> 6][c] = q;
  __syncthreads();
  if (t < 64) {
    float S = (ls[0][t] + ls[1][t]) + (ls[2][t] + ls[3][t]);
    float Q = (lq[0][t] + lq[1][t]) + (lq[2][t] + lq[3][t]);
    part[blockIdx.x * 128 + t] = S;
    part[blockIdx.x * 128 + 64 + t] = Q;
  }
}

// ---------------- reduce [nrow][ncol] partials -> [ncol] ----------------
__global__ void k_red(const float* __restrict__ part, float* __restrict__ outv,
                      int ncol, int nrow) {
  int c = blockIdx.x * 64 + threadIdx.x;
  float a0 = 0, a1 = 0, a2 = 0, a3 = 0;
  for (int r = 0; r < nrow; r += 4) {
    a0 += part[(size_t)(r + 0) * ncol + c];
    a1 += part[(size_t)(r + 1) * ncol + c];
    a2 += part[(size_t)(r + 2) * ncol + c];
    a3 += part[(size_t)(r + 3) * ncol + c];
  }
  outv[c] = (a0 + a1) + (a2 + a3);
}

// ------- BN1-apply + conv2 (64->128) + stats2 partials + max/min over K -------
__global__ __launch_bounds__(256) void k_conv2(const float* __restrict__ y1,
                                               const float* __restrict__ W1,
                                               const float* __restrict__ st1,
                                               const float* __restrict__ g0,
                                               const float* __restrict__ b0,
                                               float* __restrict__ part2,
                                               float* __restrict__ mmax,
                                               float* __restrict__ mmin) {
  __shared__ float w1t[64][128];
  __shared__ float X2[32][69];
  __shared__ float a1s[64], bb1s[64];
  const int t = threadIdx.x;
  if (t < 64) {
    float s = st1[t], q = st1[64 + t];
    float m = s * (1.f / 131072.f);
    float v = fmaxf(q * (1.f / 131072.f) - m * m, 0.f);
    float inv = 1.f / sqrtf(v + 1e-5f);
    float a = g0[t] * inv;
    a1s[t] = a;
    bb1s[t] = b0[t] - m * a;
  }
  for (int idx = t; idx < 64 * 128; idx += 256) {
    int i = idx >> 7, c = idx & 127;
    w1t[i][c] = W1[c * 64 + i];
  }
  const int kg = (t & 7) << 2;   // 4 neighbor slots
  const int cb = (t >> 3) << 2;  // 4 channels
  const int gk = t >> 3, c8 = (t & 7) << 3;
  float ts[4] = {}, tq[4] = {};
  for (int cc = 0; cc < 8; ++cc) {
    int cs = blockIdx.x * 8 + cc;
    int b = cs >> 10, sc = cs & 1023;
    __syncthreads();
    {
      const float* src = y1 + ((size_t)cs * K_ + gk) * 64 + c8;
      float4 v0 = *(const float4*)src;
      float4 v1 = *(const float4*)(src + 4);
      float vv[8] = {v0.x, v0.y, v0.z, v0.w, v1.x, v1.y, v1.z, v1.w};
#pragma unroll
      for (int j = 0; j < 8; ++j) {
        int c = c8 + j;
        X2[gk][c] = fmaxf(fmaf(a1s[c], vv[j], bb1s[c]), 0.f);
      }
    }
    __syncthreads();
    float acc[4][4] = {};
    for (int i = 0; i < 64; ++i) {
      const float4 w = *(const float4*)&w1t[i][cb];
#pragma unroll
      for (int kk = 0; kk < 4; ++kk) {
        float xv = X2[kg + kk][i];
        acc[kk][0] = fmaf(w.x, xv, acc[kk][0]);
        acc[kk][1] = fmaf(w.y, xv, acc[kk][1]);
        acc[kk][2] = fmaf(w.z, xv, acc[kk][2]);
        acc[kk][3] = fmaf(w.w, xv, acc[kk][3]);
      }
    }
    float mx[4], mn[4];
#pragma unroll
    for (int j = 0; j < 4; ++j) {
      mx[j] = fmaxf(fmaxf(acc[0][j], acc[1][j]), fmaxf(acc[2][j], acc[3][j]));
      mn[j] = fminf(fminf(acc[0][j], acc[1][j]), fminf(acc[2][j], acc[3][j]));
      ts[j] += (acc[0][j] + acc[1][j]) + (acc[2][j] + acc[3][j]);
      tq[j] += (acc[0][j] * acc[0][j] + acc[1][j] * acc[1][j]) +
               (acc[2][j] * acc[2][j] + acc[3][j] * acc[3][j]);
    }
#pragma unroll
    for (int off = 1; off < 8; off <<= 1) {
#pragma unroll
      for (int j = 0; j < 4; ++j) {
        mx[j] = fmaxf(mx[j], __shfl_xor(mx[j], off));
        mn[j] = fminf(mn[j], __shfl_xor(mn[j], off));
      }
    }
    if ((t & 7) == 0) {
#pragma unroll
      for (int j = 0; j < 4; ++j) {
        size_t o = ((size_t)b * 128 + cb + j) * 1024 + sc;
        mmax[o] = mx[j];
        mmin[o] = mn[j];
      }
    }
  }
#pragma unroll
  for (int off = 1; off < 8; off <<= 1) {
#pragma unroll
    for (int j = 0; j < 4; ++j) {
      ts[j] += __shfl_xor(ts[j], off);
      tq[j] += __shfl_xor(tq[j], off);
    }
  }
  if ((t & 7) == 0) {
#pragma unroll
    for (int j = 0; j < 4; ++j) {
      part2[blockIdx.x * 256 + cb + j] = ts[j];
      part2[blockIdx.x * 256 + 128 + cb + j] = tq[j];
    }
  }
}

// ---------------- finalize: BN2 affine on max/min + ReLU ----------------
__global__ __launch_bounds__(256) void k_final(const float* __restrict__ st2,
                                               const float* __restrict__ g1,
                                               const float* __restrict__ b1,
                                               const float* __restrict__ mmax,
                                               const float* __restrict__ mmin,
                                               float* __restrict__ out) {
  int tid = blockIdx.x * 256 + threadIdx.x;
  int c = (tid >> 10) & 127;
  float s = st2[c], q = st2[128 + c];
  float m = s * (1.f / 131072.f);
  float v = fmaxf(q * (1.f / 131072.f) - m * m, 0.f);
  float inv = 1.f / sqrtf(v + 1e-5f);
  float a = g1[c] * inv;
  float bb = b1[c] - m * a;
  // max over K of relu(a*x+bb) == relu(a * (a>=0 ? max : min) + bb)
  float x = (a >= 0.f) ? mmax[tid] : mmin[tid];
  out[12288 + tid] = fmaxf(fmaf(a, x, bb), 0.f);
}

extern "C" void kernel_launch(void* const* d_in, const int* in_sizes, int n_in,
                              void* d_out, int out_size, void* d_ws, size_t ws_size,
                              hipStream_t stream) {
  const float* xyz = (const float*)d_in[0];
  const float* features = (const float*)d_in[1];
  const float* W0 = (const float*)d_in[2];
  const float* g0 = (const float*)d_in[3];
  const float* b0 = (const float*)d_in[4];
  const float* W1 = (const float*)d_in[5];
  const float* g1 = (const float*)d_in[6];
  const float* b1 = (const float*)d_in[7];
  float* out = (float*)d_out;
  float* ws = (float*)d_ws;

  float* ft = ws;                                   // 4,194,304 f
  float* y1 = ft + (size_t)4 * 16384 * 64;          // 8,388,608 f
  float* part1 = y1 + (size_t)4 * 1024 * 32 * 64;   // 65,536 f
  float* part2 = part1 + 512 * 128;                 // 131,072 f
  float* st1 = part2 + 512 * 256;                   // 128 f
  float* st2 = st1 + 128;                           // 256 f
  float* mmax = st2 + 256;                          // 524,288 f
  float* mmin = mmax + (size_t)4 * 128 * 1024;      // 524,288 f
  int* bidx = (int*)(mmin + (size_t)4 * 128 * 1024);// 131,072 i
  if (ws_size < (size_t)(13828480 + 131072) * 4) return;  // workspace guard

  float* nxyz = out;  // new_xyz occupies out[0..12288)

  k_transpose<<<1024, 256, 0, stream>>>(features, ft);
  k_fps<<<4, 1024, 0, stream>>>(xyz, nxyz);
  k_ball<<<1024, 256, 0, stream>>>(xyz, nxyz, bidx);
  k_conv1<<<512, 256, 0, stream>>>(xyz, ft, nxyz, bidx, W0, y1);
  k_stats1<<<512, 256, 0, stream>>>(y1, part1);
  k_red<<<2, 64, 0, stream>>>(part1, st1, 128, 512);
  k_conv2<<<512, 256, 0, stream>>>(y1, W1, st1, g0, b0, part2, mmax, mmin);
  k_red<<<4, 64, 0, stream>>>(part2, st2, 256, 512);
  k_final<<<2048, 256, 0, stream>>>(st2, g1, b1, mmax, mmin, out);
}